// Round 1
// baseline (391.747 us; speedup 1.0000x reference)
//
#include <hip/hip_runtime.h>

#define NODES 100000
#define EDGES 3200000
#define D 128
#define NBUCKET ((NODES + 255) / 256)    // 391 dst-buckets of 256 nodes
#define CH 8192                          // edges per binning block
#define NB_BIN ((EDGES + CH - 1) / CH)   // 391 binning blocks
#define CAP 10240                        // static per-bucket slot capacity (actual max ~8550)

typedef unsigned short us8 __attribute__((ext_vector_type(8)));
typedef short bf16x8 __attribute__((ext_vector_type(8)));
typedef float f32x4 __attribute__((ext_vector_type(4)));
typedef float f32x2 __attribute__((ext_vector_type(2)));

__device__ __forceinline__ unsigned short f32_to_bf16_rn(float f) {
    unsigned u = __float_as_uint(f);
    unsigned r = (u + 0x7FFFu + ((u >> 16) & 1u)) >> 16;   // RNE; no NaN inputs here
    return (unsigned short)r;
}

// unpack a u32 holding two bf16 channels -> f32x2 {lo, hi} (1 lshl + 1 and)
__device__ __forceinline__ f32x2 bfpair(unsigned u) {
    f32x2 r;
    r.x = __uint_as_float(u << 16);
    r.y = __uint_as_float(u & 0xffff0000u);
    return r;
}

// ---------------- w prep: fp32 [128][128] -> bf16 in B-fragment order -------
__global__ __launch_bounds__(256) void wprep(const float* __restrict__ w,
                                             unsigned short* __restrict__ wt) {
    int i = blockIdx.x * 256 + threadIdx.x;
    if (i >= 16384) return;
    int j  = i & 7;
    int l  = (i >> 3) & 63;
    int c  = (i >> 9) & 3;
    int ct = i >> 11;
    int k   = 32 * c + ((l >> 4) << 3) + j;
    int col = (ct << 4) + (l & 15);
    wt[i] = f32_to_bf16_rn(w[k * D + col]);
}

// ---------------- GEMM via MFMA: h = bf16(x) @ bf16(w) ----------------------
// hb is written PLANE-SPLIT: hb[plane][node][64] bf16, plane = ch>>6.
// This makes the aggregate gather footprint 12.8 MB per phase (vs 25.6).
__global__ __launch_bounds__(256) void gemm_mfma(const float* __restrict__ x,
                                                 const unsigned short* __restrict__ wt,
                                                 unsigned short* __restrict__ hb) {
    __shared__ unsigned short wl[16384];   // 32 KB
    const int tid = threadIdx.x;
    for (int i = tid; i < 2048; i += 256)
        ((us8*)wl)[i] = ((const us8*)wt)[i];
    __syncthreads();

    const int wave = tid >> 6, lane = tid & 63;
    const long r0 = ((long)blockIdx.x * 4 + wave) * 16;
    if (r0 >= NODES) return;
    const int m = lane & 15, q = lane >> 4;
    const float* xr = x + (r0 + m) * D;

    f32x4 acc[8];
#pragma unroll
    for (int ct = 0; ct < 8; ct++) acc[ct] = (f32x4){0.f, 0.f, 0.f, 0.f};

#pragma unroll
    for (int c = 0; c < 4; c++) {
        const int k0 = 32 * c + 8 * q;
        float4 xa = *(const float4*)(xr + k0);
        float4 xb = *(const float4*)(xr + k0 + 4);
        bf16x8 a;
        a[0] = (short)f32_to_bf16_rn(xa.x);
        a[1] = (short)f32_to_bf16_rn(xa.y);
        a[2] = (short)f32_to_bf16_rn(xa.z);
        a[3] = (short)f32_to_bf16_rn(xa.w);
        a[4] = (short)f32_to_bf16_rn(xb.x);
        a[5] = (short)f32_to_bf16_rn(xb.y);
        a[6] = (short)f32_to_bf16_rn(xb.z);
        a[7] = (short)f32_to_bf16_rn(xb.w);
#pragma unroll
        for (int ct = 0; ct < 8; ct++) {
            bf16x8 bfr = *(const bf16x8*)&wl[(((ct << 2) + c) * 64 + lane) * 8];
            acc[ct] = __builtin_amdgcn_mfma_f32_16x16x32_bf16(a, bfr, acc[ct], 0, 0, 0);
        }
    }

    // C/D: col = lane&15, row = (lane>>4)*4 + reg. ch = ct*16+m -> plane ct>>2.
#pragma unroll
    for (int ct = 0; ct < 8; ct++) {
        unsigned short* hp = hb + (size_t)(ct >> 2) * (NODES * 64) + ((ct & 3) * 16 + m);
#pragma unroll
        for (int r = 0; r < 4; r++) {
            int row = q * 4 + r;
            hp[(r0 + row) * 64] = f32_to_bf16_rn(acc[ct][r]);
        }
    }
}

// ---------------- static bucket cursors (replaces hist+scan) ----------------
__global__ __launch_bounds__(256) void init_bcur(int* __restrict__ bcur) {
    int i = blockIdx.x * 256 + threadIdx.x;
    if (i < NBUCKET) bcur[i] = i * CAP;
}

// ---------------- pass 1: bin edges by dst>>8 into static bucket regions ----
__global__ __launch_bounds__(256) void bin_pass1(const int* __restrict__ esrc,
                                                 const int* __restrict__ edst,
                                                 const float* __restrict__ eval,
                                                 int* __restrict__ bcur,
                                                 unsigned* __restrict__ tpk,
                                                 unsigned char* __restrict__ td8) {
    __shared__ int hist[NBUCKET];
    __shared__ int base[NBUCKET];
    __shared__ int lcur[NBUCKET];
    const int tid = threadIdx.x;
    const long e0 = (long)blockIdx.x * CH;

    for (int bk = tid; bk < NBUCKET; bk += 256) { hist[bk] = 0; lcur[bk] = 0; }
    __syncthreads();
    for (int i = tid; i < CH; i += 256) {
        long e = e0 + i;
        if (e < EDGES) atomicAdd(&hist[edst[e] >> 8], 1);
    }
    __syncthreads();
    for (int bk = tid; bk < NBUCKET; bk += 256) {
        int c = hist[bk];
        if (c > 0) base[bk] = atomicAdd(&bcur[bk], c);
    }
    __syncthreads();
    for (int i = tid; i < CH; i += 256) {
        long e = e0 + i;
        if (e < EDGES) {
            int dst = edst[e];
            unsigned q = (unsigned)(eval[e] * 32768.0f);
            if (q > 32767u) q = 32767u;
            unsigned pk = (q << 17) | (unsigned)esrc[e];
            int bk = dst >> 8;
            int p = base[bk] + atomicAdd(&lcur[bk], 1);
            tpk[p] = pk;
            td8[p] = (unsigned char)dst;
        }
    }
}

// ---------------- pass 2: per-node CSR offsets + L2-local scatter -----------
// rpd[node] = (epack_base << 8) | degree   (base < 2^22, degree < 256 here)
__global__ __launch_bounds__(256) void bin_pass2(const int* __restrict__ bcur,
                                                 const unsigned* __restrict__ tpk,
                                                 const unsigned char* __restrict__ td8,
                                                 int* __restrict__ rpd,
                                                 unsigned* __restrict__ epack) {
    __shared__ int cnt[256];
    __shared__ int pos[256];
    __shared__ int wsum[4];
    const int b = blockIdx.x;
    const int tid = threadIdx.x;
    const int beg = b * CAP;
    const int end = bcur[b];

    cnt[tid] = 0;
    __syncthreads();
    for (int i = beg + tid; i < end; i += 256)
        atomicAdd(&cnt[td8[i]], 1);
    __syncthreads();

    int v = cnt[tid];
    int lane = tid & 63, wid = tid >> 6;
    int s = v;
#pragma unroll
    for (int off = 1; off < 64; off <<= 1) {
        int t = __shfl_up(s, off, 64);
        if (lane >= off) s += t;
    }
    if (lane == 63) wsum[wid] = s;
    __syncthreads();
    int wbase = 0;
    for (int w = 0; w < wid; w++) wbase += wsum[w];
    int excl = wbase + s - v;
    pos[tid] = excl;
    int node = (b << 8) + tid;
    if (node < NODES) rpd[node] = ((beg + excl) << 8) | v;
    __syncthreads();

    for (int i = beg + tid; i < end; i += 256) {
        int p = beg + atomicAdd(&pos[td8[i]], 1);
        epack[p] = tpk[i];
    }
}

// ---------------- aggregation: 1 node/wave, 8-way edge-parallel, 2 planes ---
// blockIdx.y = plane (0: ch 0-63, 1: ch 64-127). x-fastest dispatch order keeps
// the two phases mostly time-separated -> 12.8 MB gather footprint per phase.
__global__ __launch_bounds__(256) void aggregate(const int* __restrict__ rpd,
                                                 const unsigned* __restrict__ epack,
                                                 const unsigned short* __restrict__ hb,
                                                 const float* __restrict__ bias,
                                                 float* __restrict__ out) {
    const int l = threadIdx.x & 63;
    const int node = blockIdx.x * 4 + (threadIdx.x >> 6);
    const int plane = blockIdx.y;
    const int li = l & 7;        // 8 lanes x 8 ch = 64 channels of this plane
    const int sub = l >> 3;      // 8 edge slots per wave
    const int v = rpd[node];
    const int beg = (int)(((unsigned)v) >> 8);
    const int end = beg + (v & 255);
    const unsigned short* hp = hb + (size_t)plane * (NODES * 64) + li * 8;

    f32x2 a0 = {0.f, 0.f}, a1 = {0.f, 0.f}, a2 = {0.f, 0.f}, a3 = {0.f, 0.f};

    // 16 edges in flight per wave: 8 subs x 2 manual streams; predicated tail.
    for (int e = beg + sub; e < end; e += 16) {
        unsigned pA = epack[e];
        unsigned pB = 0u;
        if (e + 8 < end) pB = epack[e + 8];
        int sA = pA & 0x1FFFF;
        int sB = pB & 0x1FFFF;             // pB==0 -> row 0, weight 0 (harmless)
        float vA = (float)(pA >> 17) * (1.f / 32768.f);
        float vB = (float)(pB >> 17) * (1.f / 32768.f);
        uint4 rA = *(const uint4*)(hp + (size_t)sA * 64);
        uint4 rB = *(const uint4*)(hp + (size_t)sB * 64);
        f32x2 wA = {vA, vA}, wB = {vB, vB};
        a0 += wA * bfpair(rA.x);
        a1 += wA * bfpair(rA.y);
        a2 += wA * bfpair(rA.z);
        a3 += wA * bfpair(rA.w);
        a0 += wB * bfpair(rB.x);
        a1 += wB * bfpair(rB.y);
        a2 += wB * bfpair(rB.z);
        a3 += wB * bfpair(rB.w);
    }

    float r[8] = {a0.x, a0.y, a1.x, a1.y, a2.x, a2.y, a3.x, a3.y};
#pragma unroll
    for (int k = 0; k < 8; k++) {
        r[k] += __shfl_xor(r[k], 8, 64);
        r[k] += __shfl_xor(r[k], 16, 64);
        r[k] += __shfl_xor(r[k], 32, 64);
    }

    if (sub == 0) {
        const float* bp = bias + plane * 64 + li * 8;
        float4 b0 = *(const float4*)bp;
        float4 b1 = *(const float4*)(bp + 4);
        float4 o0, o1;
        o0.x = fmaxf(r[0] + b0.x, 0.f);
        o0.y = fmaxf(r[1] + b0.y, 0.f);
        o0.z = fmaxf(r[2] + b0.z, 0.f);
        o0.w = fmaxf(r[3] + b0.w, 0.f);
        o1.x = fmaxf(r[4] + b1.x, 0.f);
        o1.y = fmaxf(r[5] + b1.y, 0.f);
        o1.z = fmaxf(r[6] + b1.z, 0.f);
        o1.w = fmaxf(r[7] + b1.w, 0.f);
        float* op = out + (size_t)node * D + plane * 64 + li * 8;
        *(float4*)op = o0;
        *(float4*)(op + 4) = o1;
    }
}

extern "C" void kernel_launch(void* const* d_in, const int* in_sizes, int n_in,
                              void* d_out, int out_size, void* d_ws, size_t ws_size,
                              hipStream_t stream) {
    const float* x    = (const float*)d_in[0];
    const int*   esrc = (const int*)  d_in[1];
    const int*   edst = (const int*)  d_in[2];
    const float* eval = (const float*)d_in[3];
    const float* w    = (const float*)d_in[4];
    const float* b    = (const float*)d_in[5];
    float* out = (float*)d_out;

    // workspace layout (bytes), total 62,069,504 (< 64,438,976 proven available)
    char* ws = (char*)d_ws;
    const size_t OFF_H    = 0;                       // 25,600,000 (bf16 h, 2 planes)
    const size_t OFF_WT   = 25600000;                // 32,768
    const size_t OFF_RPD  = OFF_WT   + 32768;        // 400,000 -> pad 400,128
    const size_t OFF_BCUR = OFF_RPD  + 400128;       // 2,048
    const size_t OFF_TPK  = OFF_BCUR + 2048;         // 391*CAP*4 = 16,015,360
    const size_t OFF_TD8  = OFF_TPK  + 16015360;     // 391*CAP   =  4,003,840
    const size_t OFF_EPK  = OFF_TD8  + 4003840;      // 391*CAP*4 = 16,015,360

    unsigned short* hb   = (unsigned short*)(ws + OFF_H);
    unsigned short* wt   = (unsigned short*)(ws + OFF_WT);
    int*            rpd  = (int*)           (ws + OFF_RPD);
    int*            bcur = (int*)           (ws + OFF_BCUR);
    unsigned*       tpk  = (unsigned*)      (ws + OFF_TPK);
    unsigned char*  td8  = (unsigned char*) (ws + OFF_TD8);
    unsigned*       epack= (unsigned*)      (ws + OFF_EPK);

    wprep<<<64, 256, 0, stream>>>(w, wt);
    gemm_mfma<<<(NODES + 63) / 64, 256, 0, stream>>>(x, wt, hb);
    init_bcur<<<2, 256, 0, stream>>>(bcur);
    bin_pass1<<<NB_BIN, 256, 0, stream>>>(esrc, edst, eval, bcur, tpk, td8);
    bin_pass2<<<NBUCKET, 256, 0, stream>>>(bcur, tpk, td8, rpd, epack);
    aggregate<<<dim3(NODES / 4, 2), 256, 0, stream>>>(rpd, epack, hb, b, out);
}

// Round 2
// 311.078 us; speedup vs baseline: 1.2593x; 1.2593x over previous
//
#include <hip/hip_runtime.h>

#define NODES 100000
#define EDGES 3200000
#define D 128
#define NBUCKET ((NODES + 255) / 256)    // 391 dst-buckets of 256 nodes
#define NBUCKP 392                       // padded even for pairwise scan
#define CH 4096                          // edges per binning block
#define NB_BIN ((EDGES + CH - 1) / CH)   // 782 binning blocks
#define CAP 10240                        // static per-bucket slot capacity (actual max ~8550)

typedef unsigned short us8 __attribute__((ext_vector_type(8)));
typedef short bf16x8 __attribute__((ext_vector_type(8)));
typedef float f32x4 __attribute__((ext_vector_type(4)));
typedef float f32x2 __attribute__((ext_vector_type(2)));

__device__ __forceinline__ unsigned short f32_to_bf16_rn(float f) {
    unsigned u = __float_as_uint(f);
    unsigned r = (u + 0x7FFFu + ((u >> 16) & 1u)) >> 16;   // RNE; no NaN inputs here
    return (unsigned short)r;
}

// unpack a u32 holding two bf16 channels -> f32x2 {lo, hi}
__device__ __forceinline__ f32x2 bfpair(unsigned u) {
    f32x2 r;
    r.x = __uint_as_float(u << 16);
    r.y = __uint_as_float(u & 0xffff0000u);
    return r;
}

// ---------------- w prep: fp32 [128][128] -> bf16 in B-fragment order -------
__global__ __launch_bounds__(256) void wprep(const float* __restrict__ w,
                                             unsigned short* __restrict__ wt) {
    int i = blockIdx.x * 256 + threadIdx.x;
    if (i >= 16384) return;
    int j  = i & 7;
    int l  = (i >> 3) & 63;
    int c  = (i >> 9) & 3;
    int ct = i >> 11;
    int k   = 32 * c + ((l >> 4) << 3) + j;
    int col = (ct << 4) + (l & 15);
    wt[i] = f32_to_bf16_rn(w[k * D + col]);
}

// ---------------- GEMM via MFMA: h = bf16(x) @ bf16(w) ----------------------
// hb written PLANE-SPLIT: hb[plane][node][64] bf16, plane = ch>>6.
__global__ __launch_bounds__(256) void gemm_mfma(const float* __restrict__ x,
                                                 const unsigned short* __restrict__ wt,
                                                 unsigned short* __restrict__ hb) {
    __shared__ unsigned short wl[16384];   // 32 KB
    const int tid = threadIdx.x;
    for (int i = tid; i < 2048; i += 256)
        ((us8*)wl)[i] = ((const us8*)wt)[i];
    __syncthreads();

    const int wave = tid >> 6, lane = tid & 63;
    const long r0 = ((long)blockIdx.x * 4 + wave) * 16;
    if (r0 >= NODES) return;
    const int m = lane & 15, q = lane >> 4;
    const float* xr = x + (r0 + m) * D;

    f32x4 acc[8];
#pragma unroll
    for (int ct = 0; ct < 8; ct++) acc[ct] = (f32x4){0.f, 0.f, 0.f, 0.f};

#pragma unroll
    for (int c = 0; c < 4; c++) {
        const int k0 = 32 * c + 8 * q;
        float4 xa = *(const float4*)(xr + k0);
        float4 xb = *(const float4*)(xr + k0 + 4);
        bf16x8 a;
        a[0] = (short)f32_to_bf16_rn(xa.x);
        a[1] = (short)f32_to_bf16_rn(xa.y);
        a[2] = (short)f32_to_bf16_rn(xa.z);
        a[3] = (short)f32_to_bf16_rn(xa.w);
        a[4] = (short)f32_to_bf16_rn(xb.x);
        a[5] = (short)f32_to_bf16_rn(xb.y);
        a[6] = (short)f32_to_bf16_rn(xb.z);
        a[7] = (short)f32_to_bf16_rn(xb.w);
#pragma unroll
        for (int ct = 0; ct < 8; ct++) {
            bf16x8 bfr = *(const bf16x8*)&wl[(((ct << 2) + c) * 64 + lane) * 8];
            acc[ct] = __builtin_amdgcn_mfma_f32_16x16x32_bf16(a, bfr, acc[ct], 0, 0, 0);
        }
    }

#pragma unroll
    for (int ct = 0; ct < 8; ct++) {
        unsigned short* hp = hb + (size_t)(ct >> 2) * (NODES * 64) + ((ct & 3) * 16 + m);
#pragma unroll
        for (int r = 0; r < 4; r++) {
            int row = q * 4 + r;
            hp[(r0 + row) * 64] = f32_to_bf16_rn(acc[ct][r]);
        }
    }
}

// ---------------- static bucket cursors -------------------------------------
__global__ __launch_bounds__(256) void init_bcur(int* __restrict__ bcur) {
    int i = blockIdx.x * 256 + threadIdx.x;
    if (i < NBUCKET) bcur[i] = i * CAP;
}

// ---------------- pass 1: in-LDS counting sort by bucket, coalesced writeout
// Sorted-by-bucket LDS staging converts the 64-random-stream scatter into
// run-contiguous global stores (runs avg ~10 edges -> near line-granular).
__global__ __launch_bounds__(256) void bin_pass1(const int* __restrict__ esrc,
                                                 const int* __restrict__ edst,
                                                 const float* __restrict__ eval,
                                                 int* __restrict__ bcur,
                                                 int2* __restrict__ tmp) {
    __shared__ int2 sed[CH];          // 32 KB sorted (pk, dst)
    __shared__ int hist[NBUCKP];
    __shared__ int basel[NBUCKP];
    __shared__ int lcur[NBUCKP];
    __shared__ int gbase[NBUCKP];
    __shared__ int wsum[4];
    const int tid = threadIdx.x;
    const long e0 = (long)blockIdx.x * CH;
    const int n = (int)((EDGES - e0 < CH) ? (EDGES - e0) : CH);

    for (int bk = tid; bk < NBUCKP; bk += 256) { hist[bk] = 0; lcur[bk] = 0; }
    __syncthreads();
    for (int i = tid; i < n; i += 256)
        atomicAdd(&hist[edst[e0 + i] >> 8], 1);
    __syncthreads();

    // pairwise exclusive scan of 392 bins: thread t owns bins 2t, 2t+1
    int h0 = 0, h1 = 0;
    if (tid < 196) { h0 = hist[2 * tid]; h1 = hist[2 * tid + 1]; }
    int s = h0 + h1;
    int lane = tid & 63, wid = tid >> 6;
    int sc = s;
#pragma unroll
    for (int off = 1; off < 64; off <<= 1) {
        int t = __shfl_up(sc, off, 64);
        if (lane >= off) sc += t;
    }
    if (lane == 63) wsum[wid] = sc;
    __syncthreads();
    int wb = 0;
    for (int w2 = 0; w2 < wid; w2++) wb += wsum[w2];
    int excl = wb + sc - s;
    if (tid < 196) { basel[2 * tid] = excl; basel[2 * tid + 1] = excl + h0; }
    // reserve global bucket ranges
    for (int bk = tid; bk < NBUCKET; bk += 256) {
        int c = hist[bk];
        if (c > 0) gbase[bk] = atomicAdd(&bcur[bk], c);
    }
    __syncthreads();

    // scatter into LDS, sorted by bucket
    for (int i = tid; i < n; i += 256) {
        long e = e0 + i;
        int dst = edst[e];
        unsigned q = (unsigned)(eval[e] * 32768.0f);
        if (q > 32767u) q = 32767u;
        unsigned pk = (q << 17) | (unsigned)esrc[e];
        int bk = dst >> 8;
        int lp = basel[bk] + atomicAdd(&lcur[bk], 1);
        sed[lp] = make_int2((int)pk, dst);
    }
    __syncthreads();

    // coalesced write-out: consecutive i -> consecutive global within runs
    for (int i = tid; i < n; i += 256) {
        int2 t = sed[i];
        int bk = t.y >> 8;
        tmp[gbase[bk] + (i - basel[bk])] = t;
    }
}

// ---------------- pass 2: LDS-staged bucket -> per-node CSR + in-place epack
// epack ALIASES tmp: bucket b's epack slots (u32 index 2*b*CAP + j) occupy the
// front half of bucket b's own int2 region; whole bucket staged to LDS before
// any write, so no hazard. rpd[node] = ((2*b*CAP + excl) << 8) | degree.
__global__ __launch_bounds__(256) void bin_pass2(const int* __restrict__ bcur,
                                                 const int2* __restrict__ tmp,
                                                 int* __restrict__ rpd,
                                                 unsigned* __restrict__ epk) {
    __shared__ unsigned spk[CAP];        // 40 KB
    __shared__ unsigned char sd8[CAP];   // 10 KB
    __shared__ int cnt[256];
    __shared__ int pos[256];
    __shared__ int wsum[4];
    const int b = blockIdx.x;
    const int tid = threadIdx.x;
    const int beg = b * CAP;
    const int n = bcur[b] - beg;

    cnt[tid] = 0;
    __syncthreads();
    for (int i = tid; i < n; i += 256) {
        int2 t = tmp[beg + i];
        spk[i] = (unsigned)t.x;
        int d8 = t.y & 255;
        sd8[i] = (unsigned char)d8;
        atomicAdd(&cnt[d8], 1);
    }
    __syncthreads();

    int v = cnt[tid];
    int lane = tid & 63, wid = tid >> 6;
    int s = v;
#pragma unroll
    for (int off = 1; off < 64; off <<= 1) {
        int t = __shfl_up(s, off, 64);
        if (lane >= off) s += t;
    }
    if (lane == 63) wsum[wid] = s;
    __syncthreads();
    int wbase = 0;
    for (int w = 0; w < wid; w++) wbase += wsum[w];
    int excl = wbase + s - v;
    pos[tid] = excl;
    int node = (b << 8) + tid;
    if (node < NODES) rpd[node] = (((beg << 1) + excl) << 8) | v;
    __syncthreads();

    for (int i = tid; i < n; i += 256) {
        int p = atomicAdd(&pos[sd8[i]], 1);
        epk[(beg << 1) + p] = spk[i];
    }
}

// ---------------- aggregation: 1 node/wave, 8-way edge-parallel, 2 planes ---
__global__ __launch_bounds__(256) void aggregate(const int* __restrict__ rpd,
                                                 const unsigned* __restrict__ epack,
                                                 const unsigned short* __restrict__ hb,
                                                 const float* __restrict__ bias,
                                                 float* __restrict__ out) {
    const int l = threadIdx.x & 63;
    const int node = blockIdx.x * 4 + (threadIdx.x >> 6);
    const int plane = blockIdx.y;
    const int li = l & 7;        // 8 lanes x 8 ch = 64 channels of this plane
    const int sub = l >> 3;      // 8 edge slots per wave
    const int v = rpd[node];
    const int beg = (int)(((unsigned)v) >> 8);
    const int end = beg + (v & 255);
    const unsigned short* hp = hb + (size_t)plane * (NODES * 64) + li * 8;

    f32x2 a0 = {0.f, 0.f}, a1 = {0.f, 0.f}, a2 = {0.f, 0.f}, a3 = {0.f, 0.f};

    for (int e = beg + sub; e < end; e += 16) {
        unsigned pA = epack[e];
        unsigned pB = 0u;
        if (e + 8 < end) pB = epack[e + 8];
        int sA = pA & 0x1FFFF;
        int sB = pB & 0x1FFFF;             // pB==0 -> row 0, weight 0 (harmless)
        float vA = (float)(pA >> 17) * (1.f / 32768.f);
        float vB = (float)(pB >> 17) * (1.f / 32768.f);
        uint4 rA = *(const uint4*)(hp + (size_t)sA * 64);
        uint4 rB = *(const uint4*)(hp + (size_t)sB * 64);
        f32x2 wA = {vA, vA}, wB = {vB, vB};
        a0 += wA * bfpair(rA.x);
        a1 += wA * bfpair(rA.y);
        a2 += wA * bfpair(rA.z);
        a3 += wA * bfpair(rA.w);
        a0 += wB * bfpair(rB.x);
        a1 += wB * bfpair(rB.y);
        a2 += wB * bfpair(rB.z);
        a3 += wB * bfpair(rB.w);
    }

    float r[8] = {a0.x, a0.y, a1.x, a1.y, a2.x, a2.y, a3.x, a3.y};
#pragma unroll
    for (int k = 0; k < 8; k++) {
        r[k] += __shfl_xor(r[k], 8, 64);
        r[k] += __shfl_xor(r[k], 16, 64);
        r[k] += __shfl_xor(r[k], 32, 64);
    }

    if (sub == 0) {
        const float* bp = bias + plane * 64 + li * 8;
        float4 b0 = *(const float4*)bp;
        float4 b1 = *(const float4*)(bp + 4);
        float4 o0, o1;
        o0.x = fmaxf(r[0] + b0.x, 0.f);
        o0.y = fmaxf(r[1] + b0.y, 0.f);
        o0.z = fmaxf(r[2] + b0.z, 0.f);
        o0.w = fmaxf(r[3] + b0.w, 0.f);
        o1.x = fmaxf(r[4] + b1.x, 0.f);
        o1.y = fmaxf(r[5] + b1.y, 0.f);
        o1.z = fmaxf(r[6] + b1.z, 0.f);
        o1.w = fmaxf(r[7] + b1.w, 0.f);
        float* op = out + (size_t)node * D + plane * 64 + li * 8;
        *(float4*)op = o0;
        *(float4*)(op + 4) = o1;
    }
}

extern "C" void kernel_launch(void* const* d_in, const int* in_sizes, int n_in,
                              void* d_out, int out_size, void* d_ws, size_t ws_size,
                              hipStream_t stream) {
    const float* x    = (const float*)d_in[0];
    const int*   esrc = (const int*)  d_in[1];
    const int*   edst = (const int*)  d_in[2];
    const float* eval = (const float*)d_in[3];
    const float* w    = (const float*)d_in[4];
    const float* b    = (const float*)d_in[5];
    float* out = (float*)d_out;

    // workspace layout (bytes), total 58,065,664
    char* ws = (char*)d_ws;
    const size_t OFF_H    = 0;                       // 25,600,000 (bf16 h, 2 planes)
    const size_t OFF_WT   = 25600000;                // 32,768
    const size_t OFF_RPD  = OFF_WT   + 32768;        // 400,000 -> pad 400,128
    const size_t OFF_BCUR = OFF_RPD  + 400128;       // 2,048
    const size_t OFF_TMP  = OFF_BCUR + 2048;         // 391*CAP*8 = 32,030,720 (epack aliases)

    unsigned short* hb   = (unsigned short*)(ws + OFF_H);
    unsigned short* wt   = (unsigned short*)(ws + OFF_WT);
    int*            rpd  = (int*)           (ws + OFF_RPD);
    int*            bcur = (int*)           (ws + OFF_BCUR);
    int2*           tmp  = (int2*)          (ws + OFF_TMP);
    unsigned*       epk  = (unsigned*)      (ws + OFF_TMP);   // in-place alias

    wprep<<<64, 256, 0, stream>>>(w, wt);
    gemm_mfma<<<(NODES + 63) / 64, 256, 0, stream>>>(x, wt, hb);
    init_bcur<<<2, 256, 0, stream>>>(bcur);
    bin_pass1<<<NB_BIN, 256, 0, stream>>>(esrc, edst, eval, bcur, tmp);
    bin_pass2<<<NBUCKET, 256, 0, stream>>>(bcur, tmp, rpd, epk);
    aggregate<<<dim3(NODES / 4, 2), 256, 0, stream>>>(rpd, epk, hb, b, out);
}

// Round 3
// 307.050 us; speedup vs baseline: 1.2758x; 1.0131x over previous
//
#include <hip/hip_runtime.h>

#define NODES 100000
#define EDGES 3200000
#define D 128
#define NBUCKET ((NODES + 255) / 256)    // 391 dst-buckets of 256 nodes
#define NBUCKP 392                       // padded even for pairwise scan
#define CH 4096                          // edges per binning block
#define NB_BIN ((EDGES + CH - 1) / CH)   // 782 binning blocks
#define CAP 10240                        // static per-bucket slot capacity (actual max ~8550)

typedef unsigned short us8 __attribute__((ext_vector_type(8)));
typedef _Float16 half8 __attribute__((ext_vector_type(8)));
typedef _Float16 h2 __attribute__((ext_vector_type(2)));
typedef float f32x4 __attribute__((ext_vector_type(4)));

__device__ __forceinline__ unsigned short f32_to_f16_bits(float f) {
    return __builtin_bit_cast(unsigned short, (_Float16)f);
}
__device__ __forceinline__ h2 uh2(unsigned u) {
    return __builtin_bit_cast(h2, u);
}

// ---------------- w prep: fp32 [128][128] -> fp16 in B-fragment order -------
__global__ __launch_bounds__(256) void wprep(const float* __restrict__ w,
                                             unsigned short* __restrict__ wt) {
    int i = blockIdx.x * 256 + threadIdx.x;
    if (i >= 16384) return;
    int j  = i & 7;
    int l  = (i >> 3) & 63;
    int c  = (i >> 9) & 3;
    int ct = i >> 11;
    int k   = 32 * c + ((l >> 4) << 3) + j;
    int col = (ct << 4) + (l & 15);
    wt[i] = f32_to_f16_bits(w[k * D + col]);
}

// ---------------- GEMM via MFMA: h = fp16(x) @ fp16(w), hb fp16 row-major ---
__global__ __launch_bounds__(256) void gemm_mfma(const float* __restrict__ x,
                                                 const unsigned short* __restrict__ wt,
                                                 unsigned short* __restrict__ hb) {
    __shared__ unsigned short wl[16384];   // 32 KB
    const int tid = threadIdx.x;
    for (int i = tid; i < 2048; i += 256)
        ((us8*)wl)[i] = ((const us8*)wt)[i];
    __syncthreads();

    const int wave = tid >> 6, lane = tid & 63;
    const long r0 = ((long)blockIdx.x * 4 + wave) * 16;
    if (r0 >= NODES) return;
    const int m = lane & 15, q = lane >> 4;
    const float* xr = x + (r0 + m) * D;

    f32x4 acc[8];
#pragma unroll
    for (int ct = 0; ct < 8; ct++) acc[ct] = (f32x4){0.f, 0.f, 0.f, 0.f};

#pragma unroll
    for (int c = 0; c < 4; c++) {
        const int k0 = 32 * c + 8 * q;
        float4 xa = *(const float4*)(xr + k0);
        float4 xb = *(const float4*)(xr + k0 + 4);
        half8 a;
        a[0] = (_Float16)xa.x;
        a[1] = (_Float16)xa.y;
        a[2] = (_Float16)xa.z;
        a[3] = (_Float16)xa.w;
        a[4] = (_Float16)xb.x;
        a[5] = (_Float16)xb.y;
        a[6] = (_Float16)xb.z;
        a[7] = (_Float16)xb.w;
#pragma unroll
        for (int ct = 0; ct < 8; ct++) {
            half8 bfr = *(const half8*)&wl[(((ct << 2) + c) * 64 + lane) * 8];
            acc[ct] = __builtin_amdgcn_mfma_f32_16x16x32_f16(a, bfr, acc[ct], 0, 0, 0);
        }
    }

    // C/D: col = lane&15, row = (lane>>4)*4 + reg
#pragma unroll
    for (int ct = 0; ct < 8; ct++) {
#pragma unroll
        for (int r = 0; r < 4; r++) {
            int row = q * 4 + r;
            hb[(r0 + row) * D + ct * 16 + m] = f32_to_f16_bits(acc[ct][r]);
        }
    }
}

// ---------------- static bucket cursors -------------------------------------
__global__ __launch_bounds__(256) void init_bcur(int* __restrict__ bcur) {
    int i = blockIdx.x * 256 + threadIdx.x;
    if (i < NBUCKET) bcur[i] = i * CAP;
}

// ---------------- pass 1: in-LDS counting sort by bucket, coalesced writeout
// pk = (fp16_bits(val) << 17) | src   (val in [0,1) -> bits < 0x3C00 < 2^15)
__global__ __launch_bounds__(256) void bin_pass1(const int* __restrict__ esrc,
                                                 const int* __restrict__ edst,
                                                 const float* __restrict__ eval,
                                                 int* __restrict__ bcur,
                                                 int2* __restrict__ tmp) {
    __shared__ int2 sed[CH];          // 32 KB sorted (pk, dst)
    __shared__ int hist[NBUCKP];
    __shared__ int basel[NBUCKP];
    __shared__ int lcur[NBUCKP];
    __shared__ int gbase[NBUCKP];
    __shared__ int wsum[4];
    const int tid = threadIdx.x;
    const long e0 = (long)blockIdx.x * CH;
    const int n = (int)((EDGES - e0 < CH) ? (EDGES - e0) : CH);

    for (int bk = tid; bk < NBUCKP; bk += 256) { hist[bk] = 0; lcur[bk] = 0; }
    __syncthreads();
    for (int i = tid; i < n; i += 256)
        atomicAdd(&hist[edst[e0 + i] >> 8], 1);
    __syncthreads();

    // pairwise exclusive scan of 392 bins: thread t owns bins 2t, 2t+1
    int h0 = 0, h1 = 0;
    if (tid < 196) { h0 = hist[2 * tid]; h1 = hist[2 * tid + 1]; }
    int s = h0 + h1;
    int lane = tid & 63, wid = tid >> 6;
    int sc = s;
#pragma unroll
    for (int off = 1; off < 64; off <<= 1) {
        int t = __shfl_up(sc, off, 64);
        if (lane >= off) sc += t;
    }
    if (lane == 63) wsum[wid] = sc;
    __syncthreads();
    int wb = 0;
    for (int w2 = 0; w2 < wid; w2++) wb += wsum[w2];
    int excl = wb + sc - s;
    if (tid < 196) { basel[2 * tid] = excl; basel[2 * tid + 1] = excl + h0; }
    // reserve global bucket ranges
    for (int bk = tid; bk < NBUCKET; bk += 256) {
        int c = hist[bk];
        if (c > 0) gbase[bk] = atomicAdd(&bcur[bk], c);
    }
    __syncthreads();

    // scatter into LDS, sorted by bucket
    for (int i = tid; i < n; i += 256) {
        long e = e0 + i;
        int dst = edst[e];
        unsigned hv = (unsigned)f32_to_f16_bits(eval[e]);
        unsigned pk = (hv << 17) | (unsigned)esrc[e];
        int bk = dst >> 8;
        int lp = basel[bk] + atomicAdd(&lcur[bk], 1);
        sed[lp] = make_int2((int)pk, dst);
    }
    __syncthreads();

    // coalesced write-out: consecutive i -> consecutive global within runs
    for (int i = tid; i < n; i += 256) {
        int2 t = sed[i];
        int bk = t.y >> 8;
        tmp[gbase[bk] + (i - basel[bk])] = t;
    }
}

// ---------------- pass 2: LDS-staged bucket -> per-node CSR + in-place epack
// epack ALIASES tmp. rpd[node] = ((2*b*CAP + excl) << 8) | degree.
__global__ __launch_bounds__(256) void bin_pass2(const int* __restrict__ bcur,
                                                 const int2* __restrict__ tmp,
                                                 int* __restrict__ rpd,
                                                 unsigned* __restrict__ epk) {
    __shared__ unsigned spk[CAP];        // 40 KB
    __shared__ unsigned char sd8[CAP];   // 10 KB
    __shared__ int cnt[256];
    __shared__ int pos[256];
    __shared__ int wsum[4];
    const int b = blockIdx.x;
    const int tid = threadIdx.x;
    const int beg = b * CAP;
    const int n = bcur[b] - beg;

    cnt[tid] = 0;
    __syncthreads();
    for (int i = tid; i < n; i += 256) {
        int2 t = tmp[beg + i];
        spk[i] = (unsigned)t.x;
        int d8 = t.y & 255;
        sd8[i] = (unsigned char)d8;
        atomicAdd(&cnt[d8], 1);
    }
    __syncthreads();

    int v = cnt[tid];
    int lane = tid & 63, wid = tid >> 6;
    int s = v;
#pragma unroll
    for (int off = 1; off < 64; off <<= 1) {
        int t = __shfl_up(s, off, 64);
        if (lane >= off) s += t;
    }
    if (lane == 63) wsum[wid] = s;
    __syncthreads();
    int wbase = 0;
    for (int w = 0; w < wid; w++) wbase += wsum[w];
    int excl = wbase + s - v;
    pos[tid] = excl;
    int node = (b << 8) + tid;
    if (node < NODES) rpd[node] = (((beg << 1) + excl) << 8) | v;
    __syncthreads();

    for (int i = tid; i < n; i += 256) {
        int p = atomicAdd(&pos[sd8[i]], 1);
        epk[(beg << 1) + p] = spk[i];
    }
}

// ---------------- aggregation: 1 node/wave, 4 subs x 16 lanes, fp16 pk_fma --
// Per edge: 16 lanes x uint4 = full 256-B fp16 row, consumed by v_pk_fma_f16
// with ZERO unpack instructions. 4 edge-streams deep (16 rows in flight/wave),
// two independent fp16 acc sets. f32 conversion only at the epilogue reduce.
__global__ __launch_bounds__(256) void aggregate(const int* __restrict__ rpd,
                                                 const unsigned* __restrict__ epack,
                                                 const unsigned short* __restrict__ hb,
                                                 const float* __restrict__ bias,
                                                 float* __restrict__ out) {
    const int lane = threadIdx.x & 63;
    const int node = blockIdx.x * 4 + (threadIdx.x >> 6);
    if (node >= NODES) return;
    const int sub = lane >> 4;       // 4 edge slots per wave
    const int li  = lane & 15;       // 16 lanes x 8 ch = 128 channels
    const int v = rpd[node];
    const int beg = (int)(((unsigned)v) >> 8);
    const int end = beg + (v & 255);
    const unsigned short* hp = hb + li * 8;

    h2 aA0 = (h2)0, aA1 = (h2)0, aA2 = (h2)0, aA3 = (h2)0;
    h2 aB0 = (h2)0, aB1 = (h2)0, aB2 = (h2)0, aB3 = (h2)0;

    for (int e0 = beg + sub; e0 < end; e0 += 16) {
        int i0 = e0, i1 = e0 + 4, i2 = e0 + 8, i3 = e0 + 12;
        unsigned p0 = epack[i0];                       // i0 < end guaranteed
        unsigned p1 = (i1 < end) ? epack[i1] : 0u;     // pk=0 -> val=0, src=0
        unsigned p2 = (i2 < end) ? epack[i2] : 0u;
        unsigned p3 = (i3 < end) ? epack[i3] : 0u;

        unsigned s0 = p0 & 0x1FFFFu, s1 = p1 & 0x1FFFFu;
        unsigned s2 = p2 & 0x1FFFFu, s3 = p3 & 0x1FFFFu;
        unsigned v0 = p0 >> 17, v1 = p1 >> 17, v2 = p2 >> 17, v3 = p3 >> 17;

        uint4 r0 = *(const uint4*)(hp + (size_t)s0 * D);
        uint4 r1 = *(const uint4*)(hp + (size_t)s1 * D);
        uint4 r2 = *(const uint4*)(hp + (size_t)s2 * D);
        uint4 r3 = *(const uint4*)(hp + (size_t)s3 * D);

        h2 w0 = uh2(v0 | (v0 << 16));
        h2 w1 = uh2(v1 | (v1 << 16));
        h2 w2 = uh2(v2 | (v2 << 16));
        h2 w3 = uh2(v3 | (v3 << 16));

        aA0 = uh2(r0.x) * w0 + aA0;
        aA1 = uh2(r0.y) * w0 + aA1;
        aA2 = uh2(r0.z) * w0 + aA2;
        aA3 = uh2(r0.w) * w0 + aA3;
        aB0 = uh2(r1.x) * w1 + aB0;
        aB1 = uh2(r1.y) * w1 + aB1;
        aB2 = uh2(r1.z) * w1 + aB2;
        aB3 = uh2(r1.w) * w1 + aB3;
        aA0 = uh2(r2.x) * w2 + aA0;
        aA1 = uh2(r2.y) * w2 + aA1;
        aA2 = uh2(r2.z) * w2 + aA2;
        aA3 = uh2(r2.w) * w2 + aA3;
        aB0 = uh2(r3.x) * w3 + aB0;
        aB1 = uh2(r3.y) * w3 + aB1;
        aB2 = uh2(r3.z) * w3 + aB2;
        aB3 = uh2(r3.w) * w3 + aB3;
    }

    // merge acc sets in fp16 (few-ulp partials), then f32 for the reduce
    h2 m0 = aA0 + aB0, m1 = aA1 + aB1, m2 = aA2 + aB2, m3 = aA3 + aB3;
    float r[8];
    r[0] = (float)m0[0]; r[1] = (float)m0[1];
    r[2] = (float)m1[0]; r[3] = (float)m1[1];
    r[4] = (float)m2[0]; r[5] = (float)m2[1];
    r[6] = (float)m3[0]; r[7] = (float)m3[1];
#pragma unroll
    for (int k = 0; k < 8; k++) {
        r[k] += __shfl_xor(r[k], 16, 64);
        r[k] += __shfl_xor(r[k], 32, 64);
    }

    if (sub == 0) {
        const float* bp = bias + li * 8;
        float4 b0 = *(const float4*)bp;
        float4 b1 = *(const float4*)(bp + 4);
        float4 o0, o1;
        o0.x = fmaxf(r[0] + b0.x, 0.f);
        o0.y = fmaxf(r[1] + b0.y, 0.f);
        o0.z = fmaxf(r[2] + b0.z, 0.f);
        o0.w = fmaxf(r[3] + b0.w, 0.f);
        o1.x = fmaxf(r[4] + b1.x, 0.f);
        o1.y = fmaxf(r[5] + b1.y, 0.f);
        o1.z = fmaxf(r[6] + b1.z, 0.f);
        o1.w = fmaxf(r[7] + b1.w, 0.f);
        float* op = out + (size_t)node * D + li * 8;
        *(float4*)op = o0;
        *(float4*)(op + 4) = o1;
    }
}

extern "C" void kernel_launch(void* const* d_in, const int* in_sizes, int n_in,
                              void* d_out, int out_size, void* d_ws, size_t ws_size,
                              hipStream_t stream) {
    const float* x    = (const float*)d_in[0];
    const int*   esrc = (const int*)  d_in[1];
    const int*   edst = (const int*)  d_in[2];
    const float* eval = (const float*)d_in[3];
    const float* w    = (const float*)d_in[4];
    const float* b    = (const float*)d_in[5];
    float* out = (float*)d_out;

    // workspace layout (bytes), total 58,065,664
    char* ws = (char*)d_ws;
    const size_t OFF_H    = 0;                       // 25,600,000 (fp16 h)
    const size_t OFF_WT   = 25600000;                // 32,768
    const size_t OFF_RPD  = OFF_WT   + 32768;        // 400,000 -> pad 400,128
    const size_t OFF_BCUR = OFF_RPD  + 400128;       // 2,048
    const size_t OFF_TMP  = OFF_BCUR + 2048;         // 391*CAP*8 = 32,030,720 (epack aliases)

    unsigned short* hb   = (unsigned short*)(ws + OFF_H);
    unsigned short* wt   = (unsigned short*)(ws + OFF_WT);
    int*            rpd  = (int*)           (ws + OFF_RPD);
    int*            bcur = (int*)           (ws + OFF_BCUR);
    int2*           tmp  = (int2*)          (ws + OFF_TMP);
    unsigned*       epk  = (unsigned*)      (ws + OFF_TMP);   // in-place alias

    wprep<<<64, 256, 0, stream>>>(w, wt);
    gemm_mfma<<<(NODES + 63) / 64, 256, 0, stream>>>(x, wt, hb);
    init_bcur<<<2, 256, 0, stream>>>(bcur);
    bin_pass1<<<NB_BIN, 256, 0, stream>>>(esrc, edst, eval, bcur, tmp);
    bin_pass2<<<NBUCKET, 256, 0, stream>>>(bcur, tmp, rpd, epk);
    aggregate<<<(NODES + 3) / 4, 256, 0, stream>>>(rpd, epk, hb, b, out);
}